// Round 1
// baseline (639.687 us; speedup 1.0000x reference)
//
#include <hip/hip_runtime.h>
#include <hip/hip_bf16.h>
#include <hip/hip_fp16.h>
#include <math.h>

#define NEG_SLOPE 0.2f

typedef unsigned int uint;
typedef __bf16 bf16x8 __attribute__((ext_vector_type(8)));
typedef __bf16 bf16x4 __attribute__((ext_vector_type(4)));
typedef __bf16 bf16x2 __attribute__((ext_vector_type(2)));
typedef _Float16 f16x2 __attribute__((ext_vector_type(2)));
typedef float floatx4 __attribute__((ext_vector_type(4)));

__device__ inline float2 h2_to_f2(uint v) {
    f16x2 p = __builtin_bit_cast(f16x2, v);
    return make_float2((float)p[0], (float)p[1]);
}

// ============================ CSR build =================================

__global__ void count_deg(const int* __restrict__ dst, int* __restrict__ deg, int E) {
    int i = blockIdx.x * blockDim.x + threadIdx.x;
    if (i < E) atomicAdd(&deg[dst[i]], 1);
}

__global__ void scan_block_k(const int* __restrict__ deg, int* __restrict__ off,
                             int* __restrict__ bsum, int N) {
    __shared__ int sdata[256];
    int t = threadIdx.x;
    int base = blockIdx.x * 1024 + t * 4;
    int v0 = (base + 0 < N) ? deg[base + 0] : 0;
    int v1 = (base + 1 < N) ? deg[base + 1] : 0;
    int v2 = (base + 2 < N) ? deg[base + 2] : 0;
    int v3 = (base + 3 < N) ? deg[base + 3] : 0;
    int s = v0 + v1 + v2 + v3;
    sdata[t] = s;
    __syncthreads();
    for (int d = 1; d < 256; d <<= 1) {
        int x = (t >= d) ? sdata[t - d] : 0;
        __syncthreads();
        sdata[t] += x;
        __syncthreads();
    }
    int run = sdata[t] - s;  // exclusive prefix within block
    if (t == 255) bsum[blockIdx.x] = sdata[255];
    if (base + 0 < N) off[base + 0] = run; run += v0;
    if (base + 1 < N) off[base + 1] = run; run += v1;
    if (base + 2 < N) off[base + 2] = run; run += v2;
    if (base + 3 < N) off[base + 3] = run;
}

__global__ void scan_bsum_k(int* bsum, int G) {
    __shared__ int sdata[1024];
    int t = threadIdx.x;
    int v = (t < G) ? bsum[t] : 0;
    sdata[t] = v;
    __syncthreads();
    for (int d = 1; d < 1024; d <<= 1) {
        int x = (t >= d) ? sdata[t - d] : 0;
        __syncthreads();
        sdata[t] += x;
        __syncthreads();
    }
    if (t < G) bsum[t] = sdata[t] - v;  // exclusive
}

__global__ void add_bsum_k(int* __restrict__ off, const int* __restrict__ bsum,
                           int N, int Etot) {
    int i = blockIdx.x * blockDim.x + threadIdx.x;
    if (i < N) off[i] += bsum[i >> 10];
    else if (i == N) off[N] = Etot;
}

__global__ void copy_off_k(const int* __restrict__ off, int* __restrict__ cursor, int N) {
    int i = blockIdx.x * blockDim.x + threadIdx.x;
    if (i < N) cursor[i] = off[i];
}

// XCD-partitioned CSR scatter. part = blockIdx%8 owns dst range
// [part*nlo, part*nlo+nlo); its blocks grid-stride the WHOLE edge list and
// scatter only in-range edges. All writers of a CSR slice (~E/8*4B = 800KB)
// are heuristically on one XCD (blockIdx%8 round-robin), so the slice stays
// in that XCD's 4MiB L2 and partial-line stores MERGE before writeback.
// (Unpartitioned version measured 100-107MB WRITE_SIZE for 6.4MB payload:
// zero merging across 8 non-coherent L2s.) Correctness is independent of the
// XCD mapping — the range filter alone guarantees each edge scatters once.
__global__ void fill_csr_part(const int* __restrict__ src, const int* __restrict__ dst,
                              int* __restrict__ cursor, int* __restrict__ csr_src,
                              int E, int nlo) {
    int part = blockIdx.x & 7;
    int lo = part * nlo, hi = lo + nlo;
    int stride = (gridDim.x >> 3) * blockDim.x;
    for (int i = (blockIdx.x >> 3) * blockDim.x + threadIdx.x; i < E; i += stride) {
        int d = dst[i];
        if (d >= lo && d < hi) {
            int p = atomicAdd(&cursor[d], 1);
            csr_src[p] = src[i];
        }
    }
}

// ===================== splits (fp32 -> hi/lo bf16) =======================

__global__ void split_x_k(const float* __restrict__ in, __bf16* __restrict__ hi,
                          __bf16* __restrict__ lo, int n4) {
    int i = blockIdx.x * blockDim.x + threadIdx.x;
    if (i >= n4) return;
    float4 v = ((const float4*)in)[i];
    bf16x4 h = { (__bf16)v.x, (__bf16)v.y, (__bf16)v.z, (__bf16)v.w };
    bf16x4 l = { (__bf16)(v.x - (float)h[0]), (__bf16)(v.y - (float)h[1]),
                 (__bf16)(v.z - (float)h[2]), (__bf16)(v.w - (float)h[3]) };
    ((bf16x4*)hi)[i] = h;
    ((bf16x4*)lo)[i] = l;
}

// split + fragment-order all three 128x128 W's.
// Wf element (ct,kt,q,n16,j) holds W[k][ncol] with k = kt*32+q*8+j,
// ncol = ct*16+n16. Flat: (((ct*4+kt)*64) + q*16 + n16)*8 + j
// -> a wave's B-frag load (fixed ct,kt; lane = q*16+n16) is contiguous 1 KB.
__global__ void split_w_k(const float* __restrict__ W0, const float* __restrict__ W1,
                          const float* __restrict__ W2, __bf16* __restrict__ Wfh,
                          __bf16* __restrict__ Wfl) {
    const float* W = (blockIdx.y == 0) ? W0 : (blockIdx.y == 1) ? W1 : W2;
    size_t base = (size_t)blockIdx.y * 16384;
    int i = blockIdx.x * 256 + threadIdx.x;   // 0..16383
    int k = i >> 7, ncol = i & 127;
    int ct = ncol >> 4, n16 = ncol & 15;
    int kt = k >> 5, q = (k & 31) >> 3, j = k & 7;
    size_t flat = (size_t)(((ct * 4 + kt) * 64) + q * 16 + n16) * 8 + j;
    float v = W[i];
    __bf16 h = (__bf16)v;
    __bf16 l = (__bf16)(v - (float)h);
    Wfh[base + flat] = h;
    Wfl[base + flat] = l;
}

// ================ split-bf16 MFMA GEMM + fused alphas ====================
// h = Ah*Wh + Ah*Wl + Al*Wh  (fp32-equivalent, rel err ~2^-18).
// 256 threads = 4 waves; wave = 16-row strip x 128 cols,
// 8 col-tiles x 4 k-steps x 3 MFMAs. A frags from global (row-major bf16,
// 64B/row contiguous per load); B frags from fragment-ordered W tables
// (contiguous 1KB per wave-load, L2-resident). Epilogue: alphas from fp32
// acc (shfl_xor over n-lanes); fp16 H via LDS.

__global__ __launch_bounds__(256, 2) void gemm_split(
    const __bf16* __restrict__ Ah, const __bf16* __restrict__ Al,
    const __bf16* __restrict__ Wh, const __bf16* __restrict__ Wl,
    const float* __restrict__ avs, const float* __restrict__ avd,
    _Float16* __restrict__ Hh, float* __restrict__ asrc, float* __restrict__ adst,
    int M) {
    __shared__ _Float16 hl[64][132];
    int tid = threadIdx.x;
    int wv = tid >> 6, lane = tid & 63;
    int n = lane & 15, q = lane >> 4;

    int arow_g = blockIdx.x * 64 + wv * 16 + n;
    int arow_c = (arow_g < M) ? arow_g : (M - 1);
    const bf16x8* ah = (const bf16x8*)(Ah + (size_t)arow_c * 128);
    const bf16x8* al = (const bf16x8*)(Al + (size_t)arow_c * 128);
    bf16x8 a_h[4], a_l[4];
    #pragma unroll
    for (int kt = 0; kt < 4; ++kt) {
        a_h[kt] = ah[kt * 4 + q];   // k = kt*32 + q*8 + j
        a_l[kt] = al[kt * 4 + q];
    }

    floatx4 acc[8];
    #pragma unroll
    for (int ct = 0; ct < 8; ++ct) {
        floatx4 c = {0.f, 0.f, 0.f, 0.f};
        #pragma unroll
        for (int kt = 0; kt < 4; ++kt) {
            size_t fo = (size_t)((ct * 4 + kt) * 64 + lane);
            bf16x8 bh = ((const bf16x8*)Wh)[fo];
            bf16x8 bl = ((const bf16x8*)Wl)[fo];
            c = __builtin_amdgcn_mfma_f32_16x16x32_bf16(a_h[kt], bh, c, 0, 0, 0);
            c = __builtin_amdgcn_mfma_f32_16x16x32_bf16(a_h[kt], bl, c, 0, 0, 0);
            c = __builtin_amdgcn_mfma_f32_16x16x32_bf16(a_l[kt], bh, c, 0, 0, 0);
        }
        acc[ct] = c;
    }

    // fused alphas. D layout: row = q*4+r, col = ct*16+n.
    float ps[4] = {0.f, 0.f, 0.f, 0.f}, pd[4] = {0.f, 0.f, 0.f, 0.f};
    #pragma unroll
    for (int ct = 0; ct < 8; ++ct) {
        float sv = avs[ct * 16 + n], dv = avd[ct * 16 + n];
        #pragma unroll
        for (int r = 0; r < 4; ++r) {
            ps[r] += acc[ct][r] * sv;
            pd[r] += acc[ct][r] * dv;
        }
    }
    #pragma unroll
    for (int m = 1; m < 16; m <<= 1) {
        #pragma unroll
        for (int r = 0; r < 4; ++r) {
            ps[r] += __shfl_xor(ps[r], m, 64);
            pd[r] += __shfl_xor(pd[r], m, 64);
        }
    }
    if (n == 0) {
        #pragma unroll
        for (int r = 0; r < 4; ++r) {
            int grow = blockIdx.x * 64 + wv * 16 + q * 4 + r;
            if (grow < M) { asrc[grow] = ps[r]; adst[grow] = pd[r]; }
        }
    }

    // fp16 H store via LDS (coalesced uint)
    #pragma unroll
    for (int ct = 0; ct < 8; ++ct)
        #pragma unroll
        for (int r = 0; r < 4; ++r)
            hl[wv * 16 + q * 4 + r][ct * 16 + n] = (_Float16)acc[ct][r];
    __syncthreads();

    int r0 = blockIdx.x * 64;
    for (int i = tid; i < 64 * 64; i += 256) {
        int rr = i >> 6, cu = i & 63;
        int gr = r0 + rr;
        if (gr < M)
            ((uint*)Hh)[(size_t)gr * 64 + cu] = *(const uint*)&hl[rr][cu * 2];
    }
}

// ===================== per-edge softmax weights ==========================
// One wave per dst node. The aggregate kernel previously recomputed each
// edge weight redundantly in all 64 lanes (asrc gather + add + lrelu + exp
// per lane = ~64x wasted VALU; aggregate measured VALUBusy 82%, HBM 38%).
// Here: 1 lane per edge computes exp(lrelu(asrc[s]+adst[d])) once; the
// aggregate hot loop then just loads the weight (wave-uniform, coalesced).
// Weight values and downstream summation order are identical -> bit-same
// output.

__global__ __launch_bounds__(256) void edge_w_k(
    const float* __restrict__ asrc, const float* __restrict__ adst,
    const int* __restrict__ off, const int* __restrict__ csr_src,
    float* __restrict__ ew, float* __restrict__ wself, int N) {
    int gid = blockIdx.x * blockDim.x + threadIdx.x;
    int wid = gid >> 6, lane = gid & 63;
    if (wid >= N) return;
    float ad = adst[wid];
    if (lane == 0) {
        float e = asrc[wid] + ad;
        e = (e > 0.f) ? e : NEG_SLOPE * e;
        wself[wid] = __expf(e);
    }
    int beg = off[wid], end = off[wid + 1];
    for (int p = beg + lane; p < end; p += 64) {
        float e = asrc[csr_src[p]] + ad;
        e = (e > 0.f) ? e : NEG_SLOPE * e;
        ew[p] = __expf(e);
    }
}

// ========================= edge aggregation ==============================
// one wave per dst node; fp16 h rows (256 B, one uint/lane). Edges in masked
// chunks of 4 -> 4 independent gather chains in flight per wave.
// Weights precomputed per edge (edge_w_k); row indices are readfirstlane'd
// to SGPRs so gather addressing is SALU + SGPR-base/VGPR-lane-offset.
// Softmax weights are fp32-exact; only the averaged features carry fp16
// noise (~2^-11, non-compounding).

template <int FINAL>
__global__ __launch_bounds__(256) void aggregate_k(
    const _Float16* __restrict__ h, const float* __restrict__ ew,
    const float* __restrict__ wself, const int* __restrict__ off,
    const int* __restrict__ csr_src, const float* __restrict__ bias,
    float* __restrict__ out_f, __bf16* __restrict__ a_hi, __bf16* __restrict__ a_lo,
    int N, int E) {
    int gid = blockIdx.x * blockDim.x + threadIdx.x;
    int wid = gid >> 6, lane = gid & 63;
    if (wid >= N) return;
    const uint* hrows = (const uint*)h;   // 64 uints (128 fp16) per row
    float acc0, acc1, denom;

    {   // self loop
        float w = wself[wid];
        float2 f = h2_to_f2(hrows[(size_t)wid * 64 + lane]);
        denom = w; acc0 = w * f.x; acc1 = w * f.y;
    }

    int beg = __builtin_amdgcn_readfirstlane(off[wid]);
    int end = __builtin_amdgcn_readfirstlane(off[wid + 1]);
    int Em1 = E - 1;
    for (int j = beg; j < end; j += 4) {
        int i1 = j + 1, i2 = j + 2, i3 = j + 3;
        int c1 = (i1 < E) ? i1 : Em1;
        int c2 = (i2 < E) ? i2 : Em1;
        int c3 = (i3 < E) ? i3 : Em1;
        int s0 = __builtin_amdgcn_readfirstlane(csr_src[j]);
        int s1 = __builtin_amdgcn_readfirstlane(csr_src[c1]);
        int s2 = __builtin_amdgcn_readfirstlane(csr_src[c2]);
        int s3 = __builtin_amdgcn_readfirstlane(csr_src[c3]);
        const uint* r0 = hrows + (size_t)s0 * 64;
        const uint* r1 = hrows + (size_t)s1 * 64;
        const uint* r2 = hrows + (size_t)s2 * 64;
        const uint* r3 = hrows + (size_t)s3 * 64;
        uint v0 = r0[lane];
        uint v1 = r1[lane];
        uint v2 = r2[lane];
        uint v3 = r3[lane];
        float w0 = ew[j];
        float w1 = ew[c1];
        float w2 = ew[c2];
        float w3 = ew[c3];
        w1 = (i1 < end) ? w1 : 0.f;
        w2 = (i2 < end) ? w2 : 0.f;
        w3 = (i3 < end) ? w3 : 0.f;
        denom += (w0 + w1) + (w2 + w3);
        float2 f0 = h2_to_f2(v0), f1 = h2_to_f2(v1);
        float2 f2 = h2_to_f2(v2), f3 = h2_to_f2(v3);
        acc0 += w0 * f0.x + w1 * f1.x + w2 * f2.x + w3 * f3.x;
        acc1 += w0 * f0.y + w1 * f1.y + w2 * f2.y + w3 * f3.y;
    }

    float inv = 1.0f / denom;
    float2 b2 = ((const float2*)bias)[lane];
    float o0 = acc0 * inv + b2.x;
    float o1 = acc1 * inv + b2.y;
    if (FINAL) {
        ((float2*)out_f)[(size_t)wid * 64 + lane] = make_float2(o0, o1);
    } else {
        o0 = (o0 > 0.f) ? o0 : (__expf(o0) - 1.0f);   // ELU
        o1 = (o1 > 0.f) ? o1 : (__expf(o1) - 1.0f);
        __bf16 h0 = (__bf16)o0, h1 = (__bf16)o1;
        bf16x2 ph = { h0, h1 };
        bf16x2 pl = { (__bf16)(o0 - (float)h0), (__bf16)(o1 - (float)h1) };
        ((bf16x2*)a_hi)[(size_t)wid * 64 + lane] = ph;
        ((bf16x2*)a_lo)[(size_t)wid * 64 + lane] = pl;
    }
}

// ============================ launch =====================================

extern "C" void kernel_launch(void* const* d_in, const int* in_sizes, int n_in,
                              void* d_out, int out_size, void* d_ws, size_t ws_size,
                              hipStream_t stream) {
    const float* x = (const float*)d_in[0];
    const int* ei = (const int*)d_in[1];
    int N = in_sizes[0] / 128;
    int E = in_sizes[1] / 2;
    const int* src = ei;
    const int* dst = ei + E;

    const float* Wl_[3] = { (const float*)d_in[2], (const float*)d_in[6], (const float*)d_in[10] };
    const float* asl[3] = { (const float*)d_in[3], (const float*)d_in[7], (const float*)d_in[11] };
    const float* adl[3] = { (const float*)d_in[4], (const float*)d_in[8], (const float*)d_in[12] };
    const float* bl[3]  = { (const float*)d_in[5], (const float*)d_in[9], (const float*)d_in[13] };

    // ---- workspace (~41 MB) ----
    size_t nfeat = (size_t)N * 128;
    char* p = (char*)d_ws;
    _Float16* Hh = (_Float16*)p; p += nfeat * 2;       // fp16 gather table
    __bf16* Wfh = (__bf16*)p; p += 3 * 16384 * 2;      // fragment-ordered W hi
    __bf16* Wfl = (__bf16*)p; p += 3 * 16384 * 2;      // fragment-ordered W lo
    float* asrc = (float*)p;  p += (size_t)N * 4;
    float* adst = (float*)p;  p += (size_t)N * 4;
    int* off    = (int*)p;    p += (size_t)(N + 1) * 4;
    int* cursor = (int*)p;    p += (size_t)N * 4;
    int* bsum   = (int*)p;    p += 4096 * 4;
    float* ew    = (float*)p; p += (size_t)E * 4;      // per-edge softmax weights
    float* wself = (float*)p; p += (size_t)N * 4;      // self-loop weights
    int* csr    = (int*)p;

    // activations ping-pong through d_out: hi then lo bf16 (= 51.2 MB total)
    __bf16* A_hi = (__bf16*)d_out;
    __bf16* A_lo = A_hi + nfeat;

    int G = (N + 1023) / 1024;

    // ---- CSR build (grouped by dst) ----
    hipMemsetAsync(cursor, 0, (size_t)N * sizeof(int), stream);
    count_deg<<<(E + 255) / 256, 256, 0, stream>>>(dst, cursor, E);
    scan_block_k<<<G, 256, 0, stream>>>(cursor, off, bsum, N);
    scan_bsum_k<<<1, 1024, 0, stream>>>(bsum, G);
    add_bsum_k<<<(N + 256) / 256, 256, 0, stream>>>(off, bsum, N, E);
    copy_off_k<<<(N + 255) / 256, 256, 0, stream>>>(off, cursor, N);
    int nlo = (N + 7) / 8;
    fill_csr_part<<<1024, 256, 0, stream>>>(src, dst, cursor, csr, E, nlo);

    // ---- splits ----
    split_w_k<<<dim3(64, 3), 256, 0, stream>>>(Wl_[0], Wl_[1], Wl_[2], Wfh, Wfl);
    int n4 = (int)(nfeat / 4);
    split_x_k<<<(n4 + 255) / 256, 256, 0, stream>>>(x, A_hi, A_lo, n4);

    int gemm_blocks = (N + 63) / 64;
    int wave_blocks = (N + 3) / 4;

    for (int l = 0; l < 3; ++l) {
        gemm_split<<<gemm_blocks, 256, 0, stream>>>(
            A_hi, A_lo, Wfh + (size_t)l * 16384, Wfl + (size_t)l * 16384,
            asl[l], adl[l], Hh, asrc, adst, N);
        edge_w_k<<<wave_blocks, 256, 0, stream>>>(asrc, adst, off, csr, ew, wself, N);
        if (l < 2) {
            aggregate_k<0><<<wave_blocks, 256, 0, stream>>>(
                Hh, ew, wself, off, csr, bl[l], nullptr, A_hi, A_lo, N, E);
        } else {
            aggregate_k<1><<<wave_blocks, 256, 0, stream>>>(
                Hh, ew, wself, off, csr, bl[l], (float*)d_out, nullptr, nullptr, N, E);
        }
    }
}

// Round 2
// 609.664 us; speedup vs baseline: 1.0492x; 1.0492x over previous
//
#include <hip/hip_runtime.h>
#include <hip/hip_bf16.h>
#include <hip/hip_fp16.h>
#include <math.h>

#define NEG_SLOPE 0.2f

typedef unsigned int uint;
typedef __bf16 bf16x8 __attribute__((ext_vector_type(8)));
typedef __bf16 bf16x4 __attribute__((ext_vector_type(4)));
typedef __bf16 bf16x2 __attribute__((ext_vector_type(2)));
typedef _Float16 f16x2 __attribute__((ext_vector_type(2)));
typedef float floatx4 __attribute__((ext_vector_type(4)));

__device__ inline float2 h2_to_f2(uint v) {
    f16x2 p = __builtin_bit_cast(f16x2, v);
    return make_float2((float)p[0], (float)p[1]);
}

// ============================ CSR build =================================

// int4 edge loads + 4 independent atomic chains per thread (latency ILP).
__global__ void count_deg(const int* __restrict__ dst, int* __restrict__ deg, int E) {
    int t = blockIdx.x * blockDim.x + threadIdx.x;
    int stride = gridDim.x * blockDim.x;
    int E4 = E >> 2;
    for (int i4 = t; i4 < E4; i4 += stride) {
        int4 d4 = ((const int4*)dst)[i4];
        atomicAdd(&deg[d4.x], 1);
        atomicAdd(&deg[d4.y], 1);
        atomicAdd(&deg[d4.z], 1);
        atomicAdd(&deg[d4.w], 1);
    }
    for (int i = (E4 << 2) + t; i < E; i += stride) atomicAdd(&deg[dst[i]], 1);
}

__global__ void scan_block_k(const int* __restrict__ deg, int* __restrict__ off,
                             int* __restrict__ bsum, int N) {
    __shared__ int sdata[256];
    int t = threadIdx.x;
    int base = blockIdx.x * 1024 + t * 4;
    int v0 = (base + 0 < N) ? deg[base + 0] : 0;
    int v1 = (base + 1 < N) ? deg[base + 1] : 0;
    int v2 = (base + 2 < N) ? deg[base + 2] : 0;
    int v3 = (base + 3 < N) ? deg[base + 3] : 0;
    int s = v0 + v1 + v2 + v3;
    sdata[t] = s;
    __syncthreads();
    for (int d = 1; d < 256; d <<= 1) {
        int x = (t >= d) ? sdata[t - d] : 0;
        __syncthreads();
        sdata[t] += x;
        __syncthreads();
    }
    int run = sdata[t] - s;  // exclusive prefix within block
    if (t == 255) bsum[blockIdx.x] = sdata[255];
    if (base + 0 < N) off[base + 0] = run; run += v0;
    if (base + 1 < N) off[base + 1] = run; run += v1;
    if (base + 2 < N) off[base + 2] = run; run += v2;
    if (base + 3 < N) off[base + 3] = run;
}

__global__ void scan_bsum_k(int* bsum, int G) {
    __shared__ int sdata[1024];
    int t = threadIdx.x;
    int v = (t < G) ? bsum[t] : 0;
    sdata[t] = v;
    __syncthreads();
    for (int d = 1; d < 1024; d <<= 1) {
        int x = (t >= d) ? sdata[t - d] : 0;
        __syncthreads();
        sdata[t] += x;
        __syncthreads();
    }
    if (t < G) bsum[t] = sdata[t] - v;  // exclusive
}

__global__ void add_bsum_k(int* __restrict__ off, const int* __restrict__ bsum,
                           int N, int Etot) {
    int i = blockIdx.x * blockDim.x + threadIdx.x;
    if (i < N) off[i] += bsum[i >> 10];
    else if (i == N) off[N] = Etot;
}

__global__ void copy_off_k(const int* __restrict__ off, int* __restrict__ cursor, int N) {
    int i = blockIdx.x * blockDim.x + threadIdx.x;
    if (i < N) cursor[i] = off[i];
}

// XCD-partitioned CSR scatter. part = blockIdx%8 owns dst range
// [part*nlo, part*nlo+nlo); its blocks grid-stride the WHOLE edge list and
// scatter only in-range edges, so a CSR slice's writers sit on one XCD and
// partial-line stores merge in that XCD's L2. Round-2: int4 loads + 4
// independent exec-masked atomic chains per thread + 2048 blocks (was
// latency-bound at 75us: VALUBusy 4%, occupancy 39%, 1 chain/thread).
__global__ void fill_csr_part(const int* __restrict__ src, const int* __restrict__ dst,
                              int* __restrict__ cursor, int* __restrict__ csr_src,
                              int E, int nlo) {
    int part = blockIdx.x & 7;
    int lo = part * nlo, hi = lo + nlo;
    int stride = (gridDim.x >> 3) * blockDim.x;
    int t = (blockIdx.x >> 3) * blockDim.x + threadIdx.x;
    int E4 = E >> 2;
    for (int i4 = t; i4 < E4; i4 += stride) {
        int4 d4 = ((const int4*)dst)[i4];
        int4 s4 = ((const int4*)src)[i4];
        if (d4.x >= lo && d4.x < hi) { int p = atomicAdd(&cursor[d4.x], 1); csr_src[p] = s4.x; }
        if (d4.y >= lo && d4.y < hi) { int p = atomicAdd(&cursor[d4.y], 1); csr_src[p] = s4.y; }
        if (d4.z >= lo && d4.z < hi) { int p = atomicAdd(&cursor[d4.z], 1); csr_src[p] = s4.z; }
        if (d4.w >= lo && d4.w < hi) { int p = atomicAdd(&cursor[d4.w], 1); csr_src[p] = s4.w; }
    }
    for (int i = (E4 << 2) + t; i < E; i += stride) {
        int d = dst[i];
        if (d >= lo && d < hi) {
            int p = atomicAdd(&cursor[d], 1);
            csr_src[p] = src[i];
        }
    }
}

// ===================== splits (fp32 -> hi/lo bf16) =======================

__global__ void split_x_k(const float* __restrict__ in, __bf16* __restrict__ hi,
                          __bf16* __restrict__ lo, int n4) {
    int i = blockIdx.x * blockDim.x + threadIdx.x;
    if (i >= n4) return;
    float4 v = ((const float4*)in)[i];
    bf16x4 h = { (__bf16)v.x, (__bf16)v.y, (__bf16)v.z, (__bf16)v.w };
    bf16x4 l = { (__bf16)(v.x - (float)h[0]), (__bf16)(v.y - (float)h[1]),
                 (__bf16)(v.z - (float)h[2]), (__bf16)(v.w - (float)h[3]) };
    ((bf16x4*)hi)[i] = h;
    ((bf16x4*)lo)[i] = l;
}

// split + fragment-order all three 128x128 W's.
// Wf element (ct,kt,q,n16,j) holds W[k][ncol] with k = kt*32+q*8+j,
// ncol = ct*16+n16. Flat: (((ct*4+kt)*64) + q*16 + n16)*8 + j
// -> a wave's B-frag load (fixed ct,kt; lane = q*16+n16) is contiguous 1 KB.
__global__ void split_w_k(const float* __restrict__ W0, const float* __restrict__ W1,
                          const float* __restrict__ W2, __bf16* __restrict__ Wfh,
                          __bf16* __restrict__ Wfl) {
    const float* W = (blockIdx.y == 0) ? W0 : (blockIdx.y == 1) ? W1 : W2;
    size_t base = (size_t)blockIdx.y * 16384;
    int i = blockIdx.x * 256 + threadIdx.x;   // 0..16383
    int k = i >> 7, ncol = i & 127;
    int ct = ncol >> 4, n16 = ncol & 15;
    int kt = k >> 5, q = (k & 31) >> 3, j = k & 7;
    size_t flat = (size_t)(((ct * 4 + kt) * 64) + q * 16 + n16) * 8 + j;
    float v = W[i];
    __bf16 h = (__bf16)v;
    __bf16 l = (__bf16)(v - (float)h);
    Wfh[base + flat] = h;
    Wfl[base + flat] = l;
}

// ================ split-bf16 MFMA GEMM + fused alphas ====================
// h = Ah*Wh + Ah*Wl + Al*Wh  (fp32-equivalent, rel err ~2^-18).
// 256 threads = 4 waves; wave = 16-row strip x 128 cols,
// 8 col-tiles x 4 k-steps x 3 MFMAs. Round-2: W fragments staged once per
// block into 64KB LDS (was: every wave pulled all 64KB of Wh+Wl from L2 ->
// ~400MB of ~250cyc loads feeding a serial 3-MFMA chain; gemm measured
// ~70us, ~3x roofline). Frag reads are ds_read_b128, stride-16B = conflict
// free. LDS buffer aliased with the fp16-H epilogue staging.

__global__ __launch_bounds__(256, 2) void gemm_split(
    const __bf16* __restrict__ Ah, const __bf16* __restrict__ Al,
    const __bf16* __restrict__ Wh, const __bf16* __restrict__ Wl,
    const float* __restrict__ avs, const float* __restrict__ avd,
    _Float16* __restrict__ Hh, float* __restrict__ asrc, float* __restrict__ adst,
    int M) {
    __shared__ __align__(16) char lds_raw[65536];   // W stage; aliased as hl later
    int tid = threadIdx.x;
    int wv = tid >> 6, lane = tid & 63;
    int n = lane & 15, q = lane >> 4;

    // ---- stage Wh (32KB) -> lds[0:32768), Wl (32KB) -> lds[32768:65536)
    #pragma unroll
    for (int it = 0; it < 16; ++it) {
        int boff = it * 4096 + tid * 16;            // 4KB per iteration
        const char* s = (it < 8) ? ((const char*)Wh + boff)
                                 : ((const char*)Wl + (boff - 32768));
        *(float4*)(lds_raw + boff) = *(const float4*)s;
    }

    int arow_g = blockIdx.x * 64 + wv * 16 + n;
    int arow_c = (arow_g < M) ? arow_g : (M - 1);
    const bf16x8* ah = (const bf16x8*)(Ah + (size_t)arow_c * 128);
    const bf16x8* al = (const bf16x8*)(Al + (size_t)arow_c * 128);
    bf16x8 a_h[4], a_l[4];
    #pragma unroll
    for (int kt = 0; kt < 4; ++kt) {
        a_h[kt] = ah[kt * 4 + q];   // k = kt*32 + q*8 + j
        a_l[kt] = al[kt * 4 + q];
    }
    __syncthreads();   // W staged

    floatx4 acc[8];
    #pragma unroll
    for (int ct = 0; ct < 8; ++ct) {
        floatx4 c = {0.f, 0.f, 0.f, 0.f};
        #pragma unroll
        for (int kt = 0; kt < 4; ++kt) {
            int fo = ((ct * 4 + kt) * 64 + lane) * 16;   // byte offset, <32768
            bf16x8 bh = *(const bf16x8*)(lds_raw + fo);
            bf16x8 bl = *(const bf16x8*)(lds_raw + 32768 + fo);
            c = __builtin_amdgcn_mfma_f32_16x16x32_bf16(a_h[kt], bh, c, 0, 0, 0);
            c = __builtin_amdgcn_mfma_f32_16x16x32_bf16(a_h[kt], bl, c, 0, 0, 0);
            c = __builtin_amdgcn_mfma_f32_16x16x32_bf16(a_l[kt], bh, c, 0, 0, 0);
        }
        acc[ct] = c;
    }

    // fused alphas. D layout: row = q*4+r, col = ct*16+n.
    float ps[4] = {0.f, 0.f, 0.f, 0.f}, pd[4] = {0.f, 0.f, 0.f, 0.f};
    #pragma unroll
    for (int ct = 0; ct < 8; ++ct) {
        float sv = avs[ct * 16 + n], dv = avd[ct * 16 + n];
        #pragma unroll
        for (int r = 0; r < 4; ++r) {
            ps[r] += acc[ct][r] * sv;
            pd[r] += acc[ct][r] * dv;
        }
    }
    #pragma unroll
    for (int m = 1; m < 16; m <<= 1) {
        #pragma unroll
        for (int r = 0; r < 4; ++r) {
            ps[r] += __shfl_xor(ps[r], m, 64);
            pd[r] += __shfl_xor(pd[r], m, 64);
        }
    }
    if (n == 0) {
        #pragma unroll
        for (int r = 0; r < 4; ++r) {
            int grow = blockIdx.x * 64 + wv * 16 + q * 4 + r;
            if (grow < M) { asrc[grow] = ps[r]; adst[grow] = pd[r]; }
        }
    }

    // fp16 H store via LDS (coalesced uint). lds_raw aliased -> barrier first.
    __syncthreads();
    _Float16 (*hl)[132] = (_Float16(*)[132])lds_raw;
    #pragma unroll
    for (int ct = 0; ct < 8; ++ct)
        #pragma unroll
        for (int r = 0; r < 4; ++r)
            hl[wv * 16 + q * 4 + r][ct * 16 + n] = (_Float16)acc[ct][r];
    __syncthreads();

    int r0 = blockIdx.x * 64;
    for (int i = tid; i < 64 * 64; i += 256) {
        int rr = i >> 6, cu = i & 63;
        int gr = r0 + rr;
        if (gr < M)
            ((uint*)Hh)[(size_t)gr * 64 + cu] = *(const uint*)&hl[rr][cu * 2];
    }
}

// ===================== per-edge softmax weights ==========================
// Round-2: 4 nodes per wave (16 lanes each) — one-node-per-wave left 48/64
// lanes idle and was latency-bound (~18us for ~26MB of traffic). Same
// arithmetic, same ew values.

__global__ __launch_bounds__(256) void edge_w_k(
    const float* __restrict__ asrc, const float* __restrict__ adst,
    const int* __restrict__ off, const int* __restrict__ csr_src,
    float* __restrict__ ew, float* __restrict__ wself, int N) {
    int gid = blockIdx.x * blockDim.x + threadIdx.x;
    int wave = gid >> 6, lane = gid & 63;
    int node = wave * 4 + (lane >> 4);
    int l16 = lane & 15;
    if (node >= N) return;
    float ad = adst[node];
    int beg = off[node], end = off[node + 1];
    if (l16 == 0) {
        float e = asrc[node] + ad;
        e = (e > 0.f) ? e : NEG_SLOPE * e;
        wself[node] = __expf(e);
    }
    for (int p = beg + l16; p < end; p += 16) {
        float e = asrc[csr_src[p]] + ad;
        e = (e > 0.f) ? e : NEG_SLOPE * e;
        ew[p] = __expf(e);
    }
}

// ========================= edge aggregation ==============================
// one wave per dst node; fp16 h rows (256 B, one uint/lane). Edges in masked
// chunks of 4 -> 4 independent gather chains in flight per wave.
// Weights precomputed per edge (edge_w_k); row indices are readfirstlane'd
// to SGPRs so gather addressing is SALU + SGPR-base/VGPR-lane-offset.
// Softmax weights are fp32-exact; only the averaged features carry fp16
// noise (~2^-11, non-compounding).

template <int FINAL>
__global__ __launch_bounds__(256) void aggregate_k(
    const _Float16* __restrict__ h, const float* __restrict__ ew,
    const float* __restrict__ wself, const int* __restrict__ off,
    const int* __restrict__ csr_src, const float* __restrict__ bias,
    float* __restrict__ out_f, __bf16* __restrict__ a_hi, __bf16* __restrict__ a_lo,
    int N, int E) {
    int gid = blockIdx.x * blockDim.x + threadIdx.x;
    int wid = gid >> 6, lane = gid & 63;
    if (wid >= N) return;
    const uint* hrows = (const uint*)h;   // 64 uints (128 fp16) per row
    float acc0, acc1, denom;

    {   // self loop
        float w = wself[wid];
        float2 f = h2_to_f2(hrows[(size_t)wid * 64 + lane]);
        denom = w; acc0 = w * f.x; acc1 = w * f.y;
    }

    int beg = __builtin_amdgcn_readfirstlane(off[wid]);
    int end = __builtin_amdgcn_readfirstlane(off[wid + 1]);
    int Em1 = E - 1;
    for (int j = beg; j < end; j += 4) {
        int i1 = j + 1, i2 = j + 2, i3 = j + 3;
        int c1 = (i1 < E) ? i1 : Em1;
        int c2 = (i2 < E) ? i2 : Em1;
        int c3 = (i3 < E) ? i3 : Em1;
        int s0 = __builtin_amdgcn_readfirstlane(csr_src[j]);
        int s1 = __builtin_amdgcn_readfirstlane(csr_src[c1]);
        int s2 = __builtin_amdgcn_readfirstlane(csr_src[c2]);
        int s3 = __builtin_amdgcn_readfirstlane(csr_src[c3]);
        const uint* r0 = hrows + (size_t)s0 * 64;
        const uint* r1 = hrows + (size_t)s1 * 64;
        const uint* r2 = hrows + (size_t)s2 * 64;
        const uint* r3 = hrows + (size_t)s3 * 64;
        uint v0 = r0[lane];
        uint v1 = r1[lane];
        uint v2 = r2[lane];
        uint v3 = r3[lane];
        float w0 = ew[j];
        float w1 = ew[c1];
        float w2 = ew[c2];
        float w3 = ew[c3];
        w1 = (i1 < end) ? w1 : 0.f;
        w2 = (i2 < end) ? w2 : 0.f;
        w3 = (i3 < end) ? w3 : 0.f;
        denom += (w0 + w1) + (w2 + w3);
        float2 f0 = h2_to_f2(v0), f1 = h2_to_f2(v1);
        float2 f2 = h2_to_f2(v2), f3 = h2_to_f2(v3);
        acc0 += w0 * f0.x + w1 * f1.x + w2 * f2.x + w3 * f3.x;
        acc1 += w0 * f0.y + w1 * f1.y + w2 * f2.y + w3 * f3.y;
    }

    float inv = 1.0f / denom;
    float2 b2 = ((const float2*)bias)[lane];
    float o0 = acc0 * inv + b2.x;
    float o1 = acc1 * inv + b2.y;
    if (FINAL) {
        ((float2*)out_f)[(size_t)wid * 64 + lane] = make_float2(o0, o1);
    } else {
        o0 = (o0 > 0.f) ? o0 : (__expf(o0) - 1.0f);   // ELU
        o1 = (o1 > 0.f) ? o1 : (__expf(o1) - 1.0f);
        __bf16 h0 = (__bf16)o0, h1 = (__bf16)o1;
        bf16x2 ph = { h0, h1 };
        bf16x2 pl = { (__bf16)(o0 - (float)h0), (__bf16)(o1 - (float)h1) };
        ((bf16x2*)a_hi)[(size_t)wid * 64 + lane] = ph;
        ((bf16x2*)a_lo)[(size_t)wid * 64 + lane] = pl;
    }
}

// ============================ launch =====================================

extern "C" void kernel_launch(void* const* d_in, const int* in_sizes, int n_in,
                              void* d_out, int out_size, void* d_ws, size_t ws_size,
                              hipStream_t stream) {
    const float* x = (const float*)d_in[0];
    const int* ei = (const int*)d_in[1];
    int N = in_sizes[0] / 128;
    int E = in_sizes[1] / 2;
    const int* src = ei;
    const int* dst = ei + E;

    const float* Wl_[3] = { (const float*)d_in[2], (const float*)d_in[6], (const float*)d_in[10] };
    const float* asl[3] = { (const float*)d_in[3], (const float*)d_in[7], (const float*)d_in[11] };
    const float* adl[3] = { (const float*)d_in[4], (const float*)d_in[8], (const float*)d_in[12] };
    const float* bl[3]  = { (const float*)d_in[5], (const float*)d_in[9], (const float*)d_in[13] };

    // ---- workspace (~41 MB) ----
    size_t nfeat = (size_t)N * 128;
    char* p = (char*)d_ws;
    _Float16* Hh = (_Float16*)p; p += nfeat * 2;       // fp16 gather table
    __bf16* Wfh = (__bf16*)p; p += 3 * 16384 * 2;      // fragment-ordered W hi
    __bf16* Wfl = (__bf16*)p; p += 3 * 16384 * 2;      // fragment-ordered W lo
    float* asrc = (float*)p;  p += (size_t)N * 4;
    float* adst = (float*)p;  p += (size_t)N * 4;
    int* off    = (int*)p;    p += (size_t)(N + 1) * 4;
    int* cursor = (int*)p;    p += (size_t)N * 4;
    int* bsum   = (int*)p;    p += 4096 * 4;
    float* ew    = (float*)p; p += (size_t)E * 4;      // per-edge softmax weights
    float* wself = (float*)p; p += (size_t)N * 4;      // self-loop weights
    int* csr    = (int*)p;

    // activations ping-pong through d_out: hi then lo bf16 (= 51.2 MB total)
    __bf16* A_hi = (__bf16*)d_out;
    __bf16* A_lo = A_hi + nfeat;

    int G = (N + 1023) / 1024;

    // ---- CSR build (grouped by dst) ----
    hipMemsetAsync(cursor, 0, (size_t)N * sizeof(int), stream);
    count_deg<<<2048, 256, 0, stream>>>(dst, cursor, E);
    scan_block_k<<<G, 256, 0, stream>>>(cursor, off, bsum, N);
    scan_bsum_k<<<1, 1024, 0, stream>>>(bsum, G);
    add_bsum_k<<<(N + 256) / 256, 256, 0, stream>>>(off, bsum, N, E);
    copy_off_k<<<(N + 255) / 256, 256, 0, stream>>>(off, cursor, N);
    int nlo = (N + 7) / 8;
    fill_csr_part<<<2048, 256, 0, stream>>>(src, dst, cursor, csr, E, nlo);

    // ---- splits ----
    split_w_k<<<dim3(64, 3), 256, 0, stream>>>(Wl_[0], Wl_[1], Wl_[2], Wfh, Wfl);
    int n4 = (int)(nfeat / 4);
    split_x_k<<<(n4 + 255) / 256, 256, 0, stream>>>(x, A_hi, A_lo, n4);

    int gemm_blocks = (N + 63) / 64;
    int wave_blocks = (N + 3) / 4;
    int ew_blocks = (N + 15) / 16;

    for (int l = 0; l < 3; ++l) {
        gemm_split<<<gemm_blocks, 256, 0, stream>>>(
            A_hi, A_lo, Wfh + (size_t)l * 16384, Wfl + (size_t)l * 16384,
            asl[l], adl[l], Hh, asrc, adst, N);
        edge_w_k<<<ew_blocks, 256, 0, stream>>>(asrc, adst, off, csr, ew, wself, N);
        if (l < 2) {
            aggregate_k<0><<<wave_blocks, 256, 0, stream>>>(
                Hh, ew, wself, off, csr, bl[l], nullptr, A_hi, A_lo, N, E);
        } else {
            aggregate_k<1><<<wave_blocks, 256, 0, stream>>>(
                Hh, ew, wself, off, csr, bl[l], (float*)d_out, nullptr, nullptr, N, E);
        }
    }
}

// Round 3
// 593.220 us; speedup vs baseline: 1.0783x; 1.0277x over previous
//
#include <hip/hip_runtime.h>
#include <hip/hip_bf16.h>
#include <hip/hip_fp16.h>
#include <math.h>

#define NEG_SLOPE 0.2f

typedef unsigned int uint;
typedef __bf16 bf16x8 __attribute__((ext_vector_type(8)));
typedef __bf16 bf16x4 __attribute__((ext_vector_type(4)));
typedef __bf16 bf16x2 __attribute__((ext_vector_type(2)));
typedef _Float16 f16x2 __attribute__((ext_vector_type(2)));
typedef float floatx4 __attribute__((ext_vector_type(4)));

// Atomic counters padded to one 128B cache line per node. Dense counters
// (32/line) measured 512 same-line atomics/line -> L2 serialization was the
// fill/count bottleneck (79us with VALUBusy 3%, HBM 20%: nothing busy, all
// waves in vmcnt on atomic returns).
#define CPAD 5   // <<5 ints = 128 B

__device__ inline float2 h2_to_f2(uint v) {
    f16x2 p = __builtin_bit_cast(f16x2, v);
    return make_float2((float)p[0], (float)p[1]);
}

// ============================ CSR build =================================

// int4 edge loads + 4 independent atomic chains per thread (latency ILP).
__global__ void count_deg(const int* __restrict__ dst, int* __restrict__ deg, int E) {
    int t = blockIdx.x * blockDim.x + threadIdx.x;
    int stride = gridDim.x * blockDim.x;
    int E4 = E >> 2;
    for (int i4 = t; i4 < E4; i4 += stride) {
        int4 d4 = ((const int4*)dst)[i4];
        atomicAdd(&deg[d4.x << CPAD], 1);
        atomicAdd(&deg[d4.y << CPAD], 1);
        atomicAdd(&deg[d4.z << CPAD], 1);
        atomicAdd(&deg[d4.w << CPAD], 1);
    }
    for (int i = (E4 << 2) + t; i < E; i += stride) atomicAdd(&deg[dst[i] << CPAD], 1);
}

__global__ void scan_block_k(const int* __restrict__ deg, int* __restrict__ off,
                             int* __restrict__ bsum, int N) {
    __shared__ int sdata[256];
    int t = threadIdx.x;
    int base = blockIdx.x * 1024 + t * 4;
    int v0 = (base + 0 < N) ? deg[(base + 0) << CPAD] : 0;
    int v1 = (base + 1 < N) ? deg[(base + 1) << CPAD] : 0;
    int v2 = (base + 2 < N) ? deg[(base + 2) << CPAD] : 0;
    int v3 = (base + 3 < N) ? deg[(base + 3) << CPAD] : 0;
    int s = v0 + v1 + v2 + v3;
    sdata[t] = s;
    __syncthreads();
    for (int d = 1; d < 256; d <<= 1) {
        int x = (t >= d) ? sdata[t - d] : 0;
        __syncthreads();
        sdata[t] += x;
        __syncthreads();
    }
    int run = sdata[t] - s;  // exclusive prefix within block
    if (t == 255) bsum[blockIdx.x] = sdata[255];
    if (base + 0 < N) off[base + 0] = run; run += v0;
    if (base + 1 < N) off[base + 1] = run; run += v1;
    if (base + 2 < N) off[base + 2] = run; run += v2;
    if (base + 3 < N) off[base + 3] = run;
}

__global__ void scan_bsum_k(int* bsum, int G) {
    __shared__ int sdata[1024];
    int t = threadIdx.x;
    int v = (t < G) ? bsum[t] : 0;
    sdata[t] = v;
    __syncthreads();
    for (int d = 1; d < 1024; d <<= 1) {
        int x = (t >= d) ? sdata[t - d] : 0;
        __syncthreads();
        sdata[t] += x;
        __syncthreads();
    }
    if (t < G) bsum[t] = sdata[t] - v;  // exclusive
}

// finalize off[] and seed the (padded) cursor array in one pass.
__global__ void add_bsum_k(int* __restrict__ off, const int* __restrict__ bsum,
                           int* __restrict__ cursor, int N, int Etot) {
    int i = blockIdx.x * blockDim.x + threadIdx.x;
    if (i < N) {
        int v = off[i] + bsum[i >> 10];
        off[i] = v;
        cursor[i << CPAD] = v;
    } else if (i == N) {
        off[N] = Etot;
    }
}

// XCD-partitioned CSR scatter. part = blockIdx%8 owns dst range
// [part*nlo, part*nlo+nlo); its blocks grid-stride the WHOLE edge list and
// scatter only in-range edges, so a CSR slice's writers sit on one XCD and
// partial-line stores merge in that XCD's L2. (The 8x re-read of the 12.8MB
// edge list is L3-served: FETCH measured ~50MB.) Cursors padded to a line
// per node (CPAD) to kill same-line atomic serialization.
__global__ void fill_csr_part(const int* __restrict__ src, const int* __restrict__ dst,
                              int* __restrict__ cursor, int* __restrict__ csr_src,
                              int E, int nlo) {
    int part = blockIdx.x & 7;
    int lo = part * nlo, hi = lo + nlo;
    int stride = (gridDim.x >> 3) * blockDim.x;
    int t = (blockIdx.x >> 3) * blockDim.x + threadIdx.x;
    int E4 = E >> 2;
    for (int i4 = t; i4 < E4; i4 += stride) {
        int4 d4 = ((const int4*)dst)[i4];
        int4 s4 = ((const int4*)src)[i4];
        if (d4.x >= lo && d4.x < hi) { int p = atomicAdd(&cursor[d4.x << CPAD], 1); csr_src[p] = s4.x; }
        if (d4.y >= lo && d4.y < hi) { int p = atomicAdd(&cursor[d4.y << CPAD], 1); csr_src[p] = s4.y; }
        if (d4.z >= lo && d4.z < hi) { int p = atomicAdd(&cursor[d4.z << CPAD], 1); csr_src[p] = s4.z; }
        if (d4.w >= lo && d4.w < hi) { int p = atomicAdd(&cursor[d4.w << CPAD], 1); csr_src[p] = s4.w; }
    }
    for (int i = (E4 << 2) + t; i < E; i += stride) {
        int d = dst[i];
        if (d >= lo && d < hi) {
            int p = atomicAdd(&cursor[d << CPAD], 1);
            csr_src[p] = src[i];
        }
    }
}

// ===================== splits (fp32 -> hi/lo bf16) =======================

__global__ void split_x_k(const float* __restrict__ in, __bf16* __restrict__ hi,
                          __bf16* __restrict__ lo, int n4) {
    int i = blockIdx.x * blockDim.x + threadIdx.x;
    if (i >= n4) return;
    float4 v = ((const float4*)in)[i];
    bf16x4 h = { (__bf16)v.x, (__bf16)v.y, (__bf16)v.z, (__bf16)v.w };
    bf16x4 l = { (__bf16)(v.x - (float)h[0]), (__bf16)(v.y - (float)h[1]),
                 (__bf16)(v.z - (float)h[2]), (__bf16)(v.w - (float)h[3]) };
    ((bf16x4*)hi)[i] = h;
    ((bf16x4*)lo)[i] = l;
}

// split + fragment-order all three 128x128 W's.
// Wf element (ct,kt,q,n16,j) holds W[k][ncol] with k = kt*32+q*8+j,
// ncol = ct*16+n16. Flat: (((ct*4+kt)*64) + q*16 + n16)*8 + j
// -> a wave's B-frag load (fixed ct,kt; lane = q*16+n16) is contiguous 1 KB.
__global__ void split_w_k(const float* __restrict__ W0, const float* __restrict__ W1,
                          const float* __restrict__ W2, __bf16* __restrict__ Wfh,
                          __bf16* __restrict__ Wfl) {
    const float* W = (blockIdx.y == 0) ? W0 : (blockIdx.y == 1) ? W1 : W2;
    size_t base = (size_t)blockIdx.y * 16384;
    int i = blockIdx.x * 256 + threadIdx.x;   // 0..16383
    int k = i >> 7, ncol = i & 127;
    int ct = ncol >> 4, n16 = ncol & 15;
    int kt = k >> 5, q = (k & 31) >> 3, j = k & 7;
    size_t flat = (size_t)(((ct * 4 + kt) * 64) + q * 16 + n16) * 8 + j;
    float v = W[i];
    __bf16 h = (__bf16)v;
    __bf16 l = (__bf16)(v - (float)h);
    Wfh[base + flat] = h;
    Wfl[base + flat] = l;
}

// ================ split-bf16 MFMA GEMM + fused alphas ====================
// h = Ah*Wh + Ah*Wl + Al*Wh  (fp32-equivalent, rel err ~2^-18).
// 256 threads = 4 waves; wave = 16-row strip x 128 cols,
// 8 col-tiles x 4 k-steps x 3 MFMAs. W fragments staged once per block into
// 64KB LDS; frag reads are ds_read_b128, stride-16B = conflict free. LDS
// buffer aliased with the fp16-H epilogue staging.

__global__ __launch_bounds__(256, 2) void gemm_split(
    const __bf16* __restrict__ Ah, const __bf16* __restrict__ Al,
    const __bf16* __restrict__ Wh, const __bf16* __restrict__ Wl,
    const float* __restrict__ avs, const float* __restrict__ avd,
    _Float16* __restrict__ Hh, float* __restrict__ asrc, float* __restrict__ adst,
    int M) {
    __shared__ __align__(16) char lds_raw[65536];   // W stage; aliased as hl later
    int tid = threadIdx.x;
    int wv = tid >> 6, lane = tid & 63;
    int n = lane & 15, q = lane >> 4;

    // ---- stage Wh (32KB) -> lds[0:32768), Wl (32KB) -> lds[32768:65536)
    #pragma unroll
    for (int it = 0; it < 16; ++it) {
        int boff = it * 4096 + tid * 16;            // 4KB per iteration
        const char* s = (it < 8) ? ((const char*)Wh + boff)
                                 : ((const char*)Wl + (boff - 32768));
        *(float4*)(lds_raw + boff) = *(const float4*)s;
    }

    int arow_g = blockIdx.x * 64 + wv * 16 + n;
    int arow_c = (arow_g < M) ? arow_g : (M - 1);
    const bf16x8* ah = (const bf16x8*)(Ah + (size_t)arow_c * 128);
    const bf16x8* al = (const bf16x8*)(Al + (size_t)arow_c * 128);
    bf16x8 a_h[4], a_l[4];
    #pragma unroll
    for (int kt = 0; kt < 4; ++kt) {
        a_h[kt] = ah[kt * 4 + q];   // k = kt*32 + q*8 + j
        a_l[kt] = al[kt * 4 + q];
    }
    __syncthreads();   // W staged

    floatx4 acc[8];
    #pragma unroll
    for (int ct = 0; ct < 8; ++ct) {
        floatx4 c = {0.f, 0.f, 0.f, 0.f};
        #pragma unroll
        for (int kt = 0; kt < 4; ++kt) {
            int fo = ((ct * 4 + kt) * 64 + lane) * 16;   // byte offset, <32768
            bf16x8 bh = *(const bf16x8*)(lds_raw + fo);
            bf16x8 bl = *(const bf16x8*)(lds_raw + 32768 + fo);
            c = __builtin_amdgcn_mfma_f32_16x16x32_bf16(a_h[kt], bh, c, 0, 0, 0);
            c = __builtin_amdgcn_mfma_f32_16x16x32_bf16(a_h[kt], bl, c, 0, 0, 0);
            c = __builtin_amdgcn_mfma_f32_16x16x32_bf16(a_l[kt], bh, c, 0, 0, 0);
        }
        acc[ct] = c;
    }

    // fused alphas. D layout: row = q*4+r, col = ct*16+n.
    float ps[4] = {0.f, 0.f, 0.f, 0.f}, pd[4] = {0.f, 0.f, 0.f, 0.f};
    #pragma unroll
    for (int ct = 0; ct < 8; ++ct) {
        float sv = avs[ct * 16 + n], dv = avd[ct * 16 + n];
        #pragma unroll
        for (int r = 0; r < 4; ++r) {
            ps[r] += acc[ct][r] * sv;
            pd[r] += acc[ct][r] * dv;
        }
    }
    #pragma unroll
    for (int m = 1; m < 16; m <<= 1) {
        #pragma unroll
        for (int r = 0; r < 4; ++r) {
            ps[r] += __shfl_xor(ps[r], m, 64);
            pd[r] += __shfl_xor(pd[r], m, 64);
        }
    }
    if (n == 0) {
        #pragma unroll
        for (int r = 0; r < 4; ++r) {
            int grow = blockIdx.x * 64 + wv * 16 + q * 4 + r;
            if (grow < M) { asrc[grow] = ps[r]; adst[grow] = pd[r]; }
        }
    }

    // fp16 H store via LDS (coalesced uint). lds_raw aliased -> barrier first.
    __syncthreads();
    _Float16 (*hl)[132] = (_Float16(*)[132])lds_raw;
    #pragma unroll
    for (int ct = 0; ct < 8; ++ct)
        #pragma unroll
        for (int r = 0; r < 4; ++r)
            hl[wv * 16 + q * 4 + r][ct * 16 + n] = (_Float16)acc[ct][r];
    __syncthreads();

    int r0 = blockIdx.x * 64;
    for (int i = tid; i < 64 * 64; i += 256) {
        int rr = i >> 6, cu = i & 63;
        int gr = r0 + rr;
        if (gr < M)
            ((uint*)Hh)[(size_t)gr * 64 + cu] = *(const uint*)&hl[rr][cu * 2];
    }
}

// ===================== per-edge softmax weights ==========================
// 4 nodes per wave (16 lanes each). Same arithmetic as reference; same ew
// values bit-for-bit.

__global__ __launch_bounds__(256) void edge_w_k(
    const float* __restrict__ asrc, const float* __restrict__ adst,
    const int* __restrict__ off, const int* __restrict__ csr_src,
    float* __restrict__ ew, float* __restrict__ wself, int N) {
    int gid = blockIdx.x * blockDim.x + threadIdx.x;
    int wave = gid >> 6, lane = gid & 63;
    int node = wave * 4 + (lane >> 4);
    int l16 = lane & 15;
    if (node >= N) return;
    float ad = adst[node];
    int beg = off[node], end = off[node + 1];
    if (l16 == 0) {
        float e = asrc[node] + ad;
        e = (e > 0.f) ? e : NEG_SLOPE * e;
        wself[node] = __expf(e);
    }
    for (int p = beg + l16; p < end; p += 16) {
        float e = asrc[csr_src[p]] + ad;
        e = (e > 0.f) ? e : NEG_SLOPE * e;
        ew[p] = __expf(e);
    }
}

// ========================= edge aggregation ==============================
// one wave per dst node; fp16 h rows (256 B, one uint/lane). Edges in masked
// chunks of 4 -> 4 independent gather chains in flight per wave.
// Weights precomputed per edge (edge_w_k); row indices are readfirstlane'd
// to SGPRs so gather addressing is SALU + SGPR-base/VGPR-lane-offset.
// Softmax weights are fp32-exact; only the averaged features carry fp16
// noise (~2^-11, non-compounding).

template <int FINAL>
__global__ __launch_bounds__(256) void aggregate_k(
    const _Float16* __restrict__ h, const float* __restrict__ ew,
    const float* __restrict__ wself, const int* __restrict__ off,
    const int* __restrict__ csr_src, const float* __restrict__ bias,
    float* __restrict__ out_f, __bf16* __restrict__ a_hi, __bf16* __restrict__ a_lo,
    int N, int E) {
    int gid = blockIdx.x * blockDim.x + threadIdx.x;
    int wid = gid >> 6, lane = gid & 63;
    if (wid >= N) return;
    const uint* hrows = (const uint*)h;   // 64 uints (128 fp16) per row
    float acc0, acc1, denom;

    {   // self loop
        float w = wself[wid];
        float2 f = h2_to_f2(hrows[(size_t)wid * 64 + lane]);
        denom = w; acc0 = w * f.x; acc1 = w * f.y;
    }

    int beg = __builtin_amdgcn_readfirstlane(off[wid]);
    int end = __builtin_amdgcn_readfirstlane(off[wid + 1]);
    int Em1 = E - 1;
    for (int j = beg; j < end; j += 4) {
        int i1 = j + 1, i2 = j + 2, i3 = j + 3;
        int c1 = (i1 < E) ? i1 : Em1;
        int c2 = (i2 < E) ? i2 : Em1;
        int c3 = (i3 < E) ? i3 : Em1;
        int s0 = __builtin_amdgcn_readfirstlane(csr_src[j]);
        int s1 = __builtin_amdgcn_readfirstlane(csr_src[c1]);
        int s2 = __builtin_amdgcn_readfirstlane(csr_src[c2]);
        int s3 = __builtin_amdgcn_readfirstlane(csr_src[c3]);
        const uint* r0 = hrows + (size_t)s0 * 64;
        const uint* r1 = hrows + (size_t)s1 * 64;
        const uint* r2 = hrows + (size_t)s2 * 64;
        const uint* r3 = hrows + (size_t)s3 * 64;
        uint v0 = r0[lane];
        uint v1 = r1[lane];
        uint v2 = r2[lane];
        uint v3 = r3[lane];
        float w0 = ew[j];
        float w1 = ew[c1];
        float w2 = ew[c2];
        float w3 = ew[c3];
        w1 = (i1 < end) ? w1 : 0.f;
        w2 = (i2 < end) ? w2 : 0.f;
        w3 = (i3 < end) ? w3 : 0.f;
        denom += (w0 + w1) + (w2 + w3);
        float2 f0 = h2_to_f2(v0), f1 = h2_to_f2(v1);
        float2 f2 = h2_to_f2(v2), f3 = h2_to_f2(v3);
        acc0 += w0 * f0.x + w1 * f1.x + w2 * f2.x + w3 * f3.x;
        acc1 += w0 * f0.y + w1 * f1.y + w2 * f2.y + w3 * f3.y;
    }

    float inv = 1.0f / denom;
    float2 b2 = ((const float2*)bias)[lane];
    float o0 = acc0 * inv + b2.x;
    float o1 = acc1 * inv + b2.y;
    if (FINAL) {
        ((float2*)out_f)[(size_t)wid * 64 + lane] = make_float2(o0, o1);
    } else {
        o0 = (o0 > 0.f) ? o0 : (__expf(o0) - 1.0f);   // ELU
        o1 = (o1 > 0.f) ? o1 : (__expf(o1) - 1.0f);
        __bf16 h0 = (__bf16)o0, h1 = (__bf16)o1;
        bf16x2 ph = { h0, h1 };
        bf16x2 pl = { (__bf16)(o0 - (float)h0), (__bf16)(o1 - (float)h1) };
        ((bf16x2*)a_hi)[(size_t)wid * 64 + lane] = ph;
        ((bf16x2*)a_lo)[(size_t)wid * 64 + lane] = pl;
    }
}

// ============================ launch =====================================

extern "C" void kernel_launch(void* const* d_in, const int* in_sizes, int n_in,
                              void* d_out, int out_size, void* d_ws, size_t ws_size,
                              hipStream_t stream) {
    const float* x = (const float*)d_in[0];
    const int* ei = (const int*)d_in[1];
    int N = in_sizes[0] / 128;
    int E = in_sizes[1] / 2;
    const int* src = ei;
    const int* dst = ei + E;

    const float* Wl_[3] = { (const float*)d_in[2], (const float*)d_in[6], (const float*)d_in[10] };
    const float* asl[3] = { (const float*)d_in[3], (const float*)d_in[7], (const float*)d_in[11] };
    const float* adl[3] = { (const float*)d_in[4], (const float*)d_in[8], (const float*)d_in[12] };
    const float* bl[3]  = { (const float*)d_in[5], (const float*)d_in[9], (const float*)d_in[13] };

    // ---- workspace (~41 MB) ----
    size_t nfeat = (size_t)N * 128;
    char* p = (char*)d_ws;
    _Float16* Hh = (_Float16*)p; p += nfeat * 2;       // fp16 gather table
    __bf16* Wfh = (__bf16*)p; p += 3 * 16384 * 2;      // fragment-ordered W hi
    __bf16* Wfl = (__bf16*)p; p += 3 * 16384 * 2;      // fragment-ordered W lo
    float* asrc = (float*)p;  p += (size_t)N * 4;
    float* adst = (float*)p;  p += (size_t)N * 4;
    int* off    = (int*)p;    p += (size_t)(N + 1) * 4;
    int* bsum   = (int*)p;    p += 4096 * 4;
    float* ew    = (float*)p; p += (size_t)E * 4;      // per-edge softmax weights
    float* wself = (float*)p; p += (size_t)N * 4;      // self-loop weights
    int* csr    = (int*)p;

    // Padded deg/cursor array (N*128B = 12.8MB) ALIASES the Hh region:
    // CSR build completes before the first gemm writes Hh, and Hh is
    // regenerated every layer, so there is no liveness overlap.
    int* cpad = (int*)Hh;

    // activations ping-pong through d_out: hi then lo bf16 (= 51.2 MB total)
    __bf16* A_hi = (__bf16*)d_out;
    __bf16* A_lo = A_hi + nfeat;

    int G = (N + 1023) / 1024;

    // ---- CSR build (grouped by dst) ----
    hipMemsetAsync(cpad, 0, ((size_t)N << CPAD) * sizeof(int), stream);
    count_deg<<<2048, 256, 0, stream>>>(dst, cpad, E);
    scan_block_k<<<G, 256, 0, stream>>>(cpad, off, bsum, N);
    scan_bsum_k<<<1, 1024, 0, stream>>>(bsum, G);
    add_bsum_k<<<(N + 256) / 256, 256, 0, stream>>>(off, bsum, cpad, N, E);
    int nlo = (N + 7) / 8;
    fill_csr_part<<<2048, 256, 0, stream>>>(src, dst, cpad, csr, E, nlo);

    // ---- splits ----
    split_w_k<<<dim3(64, 3), 256, 0, stream>>>(Wl_[0], Wl_[1], Wl_[2], Wfh, Wfl);
    int n4 = (int)(nfeat / 4);
    split_x_k<<<(n4 + 255) / 256, 256, 0, stream>>>(x, A_hi, A_lo, n4);

    int gemm_blocks = (N + 63) / 64;
    int wave_blocks = (N + 3) / 4;
    int ew_blocks = (N + 15) / 16;

    for (int l = 0; l < 3; ++l) {
        gemm_split<<<gemm_blocks, 256, 0, stream>>>(
            A_hi, A_lo, Wfh + (size_t)l * 16384, Wfl + (size_t)l * 16384,
            asl[l], adl[l], Hh, asrc, adst, N);
        edge_w_k<<<ew_blocks, 256, 0, stream>>>(asrc, adst, off, csr, ew, wself, N);
        if (l < 2) {
            aggregate_k<0><<<wave_blocks, 256, 0, stream>>>(
                Hh, ew, wself, off, csr, bl[l], nullptr, A_hi, A_lo, N, E);
        } else {
            aggregate_k<1><<<wave_blocks, 256, 0, stream>>>(
                Hh, ew, wself, off, csr, bl[l], (float*)d_out, nullptr, nullptr, N, E);
        }
    }
}

// Round 4
// 546.023 us; speedup vs baseline: 1.1715x; 1.0864x over previous
//
#include <hip/hip_runtime.h>
#include <hip/hip_bf16.h>
#include <hip/hip_fp16.h>
#include <math.h>

#define NEG_SLOPE 0.2f

typedef unsigned int uint;
typedef __bf16 bf16x8 __attribute__((ext_vector_type(8)));
typedef __bf16 bf16x4 __attribute__((ext_vector_type(4)));
typedef __bf16 bf16x2 __attribute__((ext_vector_type(2)));
typedef _Float16 f16x2 __attribute__((ext_vector_type(2)));
typedef float floatx4 __attribute__((ext_vector_type(4)));

// Atomic counters padded to one 128B cache line per node (CPAD). Padding
// alone was worth only ~10% (79->71us), so the atomic pass is latency-bound
// on something else; the bigger lever (this round) is doing the atomic walk
// ONCE: count_deg's atomicAdd return value IS the edge's rank in its dst
// segment. fill then becomes an atomic-free streaming scatter.
#define CPAD 5   // <<5 ints = 128 B

__device__ inline float2 h2_to_f2(uint v) {
    f16x2 p = __builtin_bit_cast(f16x2, v);
    return make_float2((float)p[0], (float)p[1]);
}

// ============================ CSR build =================================

// Single atomic pass: count degrees AND record each edge's rank within its
// dst segment (rank = atomicAdd old value). int4 loads, 4 independent
// atomic chains, sequential int4 rank store.
__global__ void count_deg_rank(const int* __restrict__ dst, int* __restrict__ deg,
                               int* __restrict__ rank, int E) {
    int t = blockIdx.x * blockDim.x + threadIdx.x;
    int stride = gridDim.x * blockDim.x;
    int E4 = E >> 2;
    for (int i4 = t; i4 < E4; i4 += stride) {
        int4 d4 = ((const int4*)dst)[i4];
        int4 r4;
        r4.x = atomicAdd(&deg[d4.x << CPAD], 1);
        r4.y = atomicAdd(&deg[d4.y << CPAD], 1);
        r4.z = atomicAdd(&deg[d4.z << CPAD], 1);
        r4.w = atomicAdd(&deg[d4.w << CPAD], 1);
        ((int4*)rank)[i4] = r4;
    }
    for (int i = (E4 << 2) + t; i < E; i += stride)
        rank[i] = atomicAdd(&deg[dst[i] << CPAD], 1);
}

__global__ void scan_block_k(const int* __restrict__ deg, int* __restrict__ off,
                             int* __restrict__ bsum, int N) {
    __shared__ int sdata[256];
    int t = threadIdx.x;
    int base = blockIdx.x * 1024 + t * 4;
    int v0 = (base + 0 < N) ? deg[(base + 0) << CPAD] : 0;
    int v1 = (base + 1 < N) ? deg[(base + 1) << CPAD] : 0;
    int v2 = (base + 2 < N) ? deg[(base + 2) << CPAD] : 0;
    int v3 = (base + 3 < N) ? deg[(base + 3) << CPAD] : 0;
    int s = v0 + v1 + v2 + v3;
    sdata[t] = s;
    __syncthreads();
    for (int d = 1; d < 256; d <<= 1) {
        int x = (t >= d) ? sdata[t - d] : 0;
        __syncthreads();
        sdata[t] += x;
        __syncthreads();
    }
    int run = sdata[t] - s;  // exclusive prefix within block
    if (t == 255) bsum[blockIdx.x] = sdata[255];
    if (base + 0 < N) off[base + 0] = run; run += v0;
    if (base + 1 < N) off[base + 1] = run; run += v1;
    if (base + 2 < N) off[base + 2] = run; run += v2;
    if (base + 3 < N) off[base + 3] = run;
}

__global__ void scan_bsum_k(int* bsum, int G) {
    __shared__ int sdata[1024];
    int t = threadIdx.x;
    int v = (t < G) ? bsum[t] : 0;
    sdata[t] = v;
    __syncthreads();
    for (int d = 1; d < 1024; d <<= 1) {
        int x = (t >= d) ? sdata[t - d] : 0;
        __syncthreads();
        sdata[t] += x;
        __syncthreads();
    }
    if (t < G) bsum[t] = sdata[t] - v;  // exclusive
}

__global__ void add_bsum_k(int* __restrict__ off, const int* __restrict__ bsum,
                           int N, int Etot) {
    int i = blockIdx.x * blockDim.x + threadIdx.x;
    if (i < N) off[i] += bsum[i >> 10];
    else if (i == N) off[N] = Etot;
}

// Atomic-free streaming scatter: p = off[dst] + rank. Edge list read ONCE
// (was 8x partition re-scan), stores fire-and-forget (no atomic->store
// dependence). off[] gather is 400KB, L2/L3-resident.
__global__ void fill_scatter(const int* __restrict__ src, const int* __restrict__ dst,
                             const int* __restrict__ rank, const int* __restrict__ off,
                             int* __restrict__ csr_src, int E) {
    int t = blockIdx.x * blockDim.x + threadIdx.x;
    int stride = gridDim.x * blockDim.x;
    int E4 = E >> 2;
    for (int i4 = t; i4 < E4; i4 += stride) {
        int4 d4 = ((const int4*)dst)[i4];
        int4 s4 = ((const int4*)src)[i4];
        int4 r4 = ((const int4*)rank)[i4];
        csr_src[off[d4.x] + r4.x] = s4.x;
        csr_src[off[d4.y] + r4.y] = s4.y;
        csr_src[off[d4.z] + r4.z] = s4.z;
        csr_src[off[d4.w] + r4.w] = s4.w;
    }
    for (int i = (E4 << 2) + t; i < E; i += stride)
        csr_src[off[dst[i]] + rank[i]] = src[i];
}

// ===================== splits (fp32 -> hi/lo bf16) =======================

__global__ void split_x_k(const float* __restrict__ in, __bf16* __restrict__ hi,
                          __bf16* __restrict__ lo, int n4) {
    int i = blockIdx.x * blockDim.x + threadIdx.x;
    if (i >= n4) return;
    float4 v = ((const float4*)in)[i];
    bf16x4 h = { (__bf16)v.x, (__bf16)v.y, (__bf16)v.z, (__bf16)v.w };
    bf16x4 l = { (__bf16)(v.x - (float)h[0]), (__bf16)(v.y - (float)h[1]),
                 (__bf16)(v.z - (float)h[2]), (__bf16)(v.w - (float)h[3]) };
    ((bf16x4*)hi)[i] = h;
    ((bf16x4*)lo)[i] = l;
}

// split + fragment-order all three 128x128 W's.
// Wf element (ct,kt,q,n16,j) holds W[k][ncol] with k = kt*32+q*8+j,
// ncol = ct*16+n16. Flat: (((ct*4+kt)*64) + q*16 + n16)*8 + j
// -> a wave's B-frag load (fixed ct,kt; lane = q*16+n16) is contiguous 1 KB.
__global__ void split_w_k(const float* __restrict__ W0, const float* __restrict__ W1,
                          const float* __restrict__ W2, __bf16* __restrict__ Wfh,
                          __bf16* __restrict__ Wfl) {
    const float* W = (blockIdx.y == 0) ? W0 : (blockIdx.y == 1) ? W1 : W2;
    size_t base = (size_t)blockIdx.y * 16384;
    int i = blockIdx.x * 256 + threadIdx.x;   // 0..16383
    int k = i >> 7, ncol = i & 127;
    int ct = ncol >> 4, n16 = ncol & 15;
    int kt = k >> 5, q = (k & 31) >> 3, j = k & 7;
    size_t flat = (size_t)(((ct * 4 + kt) * 64) + q * 16 + n16) * 8 + j;
    float v = W[i];
    __bf16 h = (__bf16)v;
    __bf16 l = (__bf16)(v - (float)h);
    Wfh[base + flat] = h;
    Wfl[base + flat] = l;
}

// ================ split-bf16 MFMA GEMM + fused alphas ====================
// h = Ah*Wh + Ah*Wl + Al*Wh  (fp32-equivalent, rel err ~2^-18).
// 256 threads = 4 waves; wave = 16-row strip x 128 cols,
// 8 col-tiles x 4 k-steps x 3 MFMAs. W fragments staged once per block into
// 64KB LDS; frag reads are ds_read_b128, stride-16B = conflict free. LDS
// buffer aliased with the fp16-H epilogue staging.

__global__ __launch_bounds__(256, 2) void gemm_split(
    const __bf16* __restrict__ Ah, const __bf16* __restrict__ Al,
    const __bf16* __restrict__ Wh, const __bf16* __restrict__ Wl,
    const float* __restrict__ avs, const float* __restrict__ avd,
    _Float16* __restrict__ Hh, float* __restrict__ asrc, float* __restrict__ adst,
    int M) {
    __shared__ __align__(16) char lds_raw[65536];   // W stage; aliased as hl later
    int tid = threadIdx.x;
    int wv = tid >> 6, lane = tid & 63;
    int n = lane & 15, q = lane >> 4;

    // ---- stage Wh (32KB) -> lds[0:32768), Wl (32KB) -> lds[32768:65536)
    #pragma unroll
    for (int it = 0; it < 16; ++it) {
        int boff = it * 4096 + tid * 16;            // 4KB per iteration
        const char* s = (it < 8) ? ((const char*)Wh + boff)
                                 : ((const char*)Wl + (boff - 32768));
        *(float4*)(lds_raw + boff) = *(const float4*)s;
    }

    int arow_g = blockIdx.x * 64 + wv * 16 + n;
    int arow_c = (arow_g < M) ? arow_g : (M - 1);
    const bf16x8* ah = (const bf16x8*)(Ah + (size_t)arow_c * 128);
    const bf16x8* al = (const bf16x8*)(Al + (size_t)arow_c * 128);
    bf16x8 a_h[4], a_l[4];
    #pragma unroll
    for (int kt = 0; kt < 4; ++kt) {
        a_h[kt] = ah[kt * 4 + q];   // k = kt*32 + q*8 + j
        a_l[kt] = al[kt * 4 + q];
    }
    __syncthreads();   // W staged

    floatx4 acc[8];
    #pragma unroll
    for (int ct = 0; ct < 8; ++ct) {
        floatx4 c = {0.f, 0.f, 0.f, 0.f};
        #pragma unroll
        for (int kt = 0; kt < 4; ++kt) {
            int fo = ((ct * 4 + kt) * 64 + lane) * 16;   // byte offset, <32768
            bf16x8 bh = *(const bf16x8*)(lds_raw + fo);
            bf16x8 bl = *(const bf16x8*)(lds_raw + 32768 + fo);
            c = __builtin_amdgcn_mfma_f32_16x16x32_bf16(a_h[kt], bh, c, 0, 0, 0);
            c = __builtin_amdgcn_mfma_f32_16x16x32_bf16(a_h[kt], bl, c, 0, 0, 0);
            c = __builtin_amdgcn_mfma_f32_16x16x32_bf16(a_l[kt], bh, c, 0, 0, 0);
        }
        acc[ct] = c;
    }

    // fused alphas. D layout: row = q*4+r, col = ct*16+n.
    float ps[4] = {0.f, 0.f, 0.f, 0.f}, pd[4] = {0.f, 0.f, 0.f, 0.f};
    #pragma unroll
    for (int ct = 0; ct < 8; ++ct) {
        float sv = avs[ct * 16 + n], dv = avd[ct * 16 + n];
        #pragma unroll
        for (int r = 0; r < 4; ++r) {
            ps[r] += acc[ct][r] * sv;
            pd[r] += acc[ct][r] * dv;
        }
    }
    #pragma unroll
    for (int m = 1; m < 16; m <<= 1) {
        #pragma unroll
        for (int r = 0; r < 4; ++r) {
            ps[r] += __shfl_xor(ps[r], m, 64);
            pd[r] += __shfl_xor(pd[r], m, 64);
        }
    }
    if (n == 0) {
        #pragma unroll
        for (int r = 0; r < 4; ++r) {
            int grow = blockIdx.x * 64 + wv * 16 + q * 4 + r;
            if (grow < M) { asrc[grow] = ps[r]; adst[grow] = pd[r]; }
        }
    }

    // fp16 H store via LDS (coalesced uint). lds_raw aliased -> barrier first.
    __syncthreads();
    _Float16 (*hl)[132] = (_Float16(*)[132])lds_raw;
    #pragma unroll
    for (int ct = 0; ct < 8; ++ct)
        #pragma unroll
        for (int r = 0; r < 4; ++r)
            hl[wv * 16 + q * 4 + r][ct * 16 + n] = (_Float16)acc[ct][r];
    __syncthreads();

    int r0 = blockIdx.x * 64;
    for (int i = tid; i < 64 * 64; i += 256) {
        int rr = i >> 6, cu = i & 63;
        int gr = r0 + rr;
        if (gr < M)
            ((uint*)Hh)[(size_t)gr * 64 + cu] = *(const uint*)&hl[rr][cu * 2];
    }
}

// ===================== per-edge softmax weights ==========================
// 4 nodes per wave (16 lanes each). Same arithmetic as reference; same ew
// values bit-for-bit.

__global__ __launch_bounds__(256) void edge_w_k(
    const float* __restrict__ asrc, const float* __restrict__ adst,
    const int* __restrict__ off, const int* __restrict__ csr_src,
    float* __restrict__ ew, float* __restrict__ wself, int N) {
    int gid = blockIdx.x * blockDim.x + threadIdx.x;
    int wave = gid >> 6, lane = gid & 63;
    int node = wave * 4 + (lane >> 4);
    int l16 = lane & 15;
    if (node >= N) return;
    float ad = adst[node];
    int beg = off[node], end = off[node + 1];
    if (l16 == 0) {
        float e = asrc[node] + ad;
        e = (e > 0.f) ? e : NEG_SLOPE * e;
        wself[node] = __expf(e);
    }
    for (int p = beg + l16; p < end; p += 16) {
        float e = asrc[csr_src[p]] + ad;
        e = (e > 0.f) ? e : NEG_SLOPE * e;
        ew[p] = __expf(e);
    }
}

// ========================= edge aggregation ==============================
// one wave per dst node; fp16 h rows (256 B, one uint/lane). Edges in masked
// chunks of 4 -> 4 independent gather chains in flight per wave.
// Weights precomputed per edge (edge_w_k); row indices are readfirstlane'd
// to SGPRs so gather addressing is SALU + SGPR-base/VGPR-lane-offset.
// Softmax weights are fp32-exact; only the averaged features carry fp16
// noise (~2^-11, non-compounding).

template <int FINAL>
__global__ __launch_bounds__(256) void aggregate_k(
    const _Float16* __restrict__ h, const float* __restrict__ ew,
    const float* __restrict__ wself, const int* __restrict__ off,
    const int* __restrict__ csr_src, const float* __restrict__ bias,
    float* __restrict__ out_f, __bf16* __restrict__ a_hi, __bf16* __restrict__ a_lo,
    int N, int E) {
    int gid = blockIdx.x * blockDim.x + threadIdx.x;
    int wid = gid >> 6, lane = gid & 63;
    if (wid >= N) return;
    const uint* hrows = (const uint*)h;   // 64 uints (128 fp16) per row
    float acc0, acc1, denom;

    {   // self loop
        float w = wself[wid];
        float2 f = h2_to_f2(hrows[(size_t)wid * 64 + lane]);
        denom = w; acc0 = w * f.x; acc1 = w * f.y;
    }

    int beg = __builtin_amdgcn_readfirstlane(off[wid]);
    int end = __builtin_amdgcn_readfirstlane(off[wid + 1]);
    int Em1 = E - 1;
    for (int j = beg; j < end; j += 4) {
        int i1 = j + 1, i2 = j + 2, i3 = j + 3;
        int c1 = (i1 < E) ? i1 : Em1;
        int c2 = (i2 < E) ? i2 : Em1;
        int c3 = (i3 < E) ? i3 : Em1;
        int s0 = __builtin_amdgcn_readfirstlane(csr_src[j]);
        int s1 = __builtin_amdgcn_readfirstlane(csr_src[c1]);
        int s2 = __builtin_amdgcn_readfirstlane(csr_src[c2]);
        int s3 = __builtin_amdgcn_readfirstlane(csr_src[c3]);
        const uint* r0 = hrows + (size_t)s0 * 64;
        const uint* r1 = hrows + (size_t)s1 * 64;
        const uint* r2 = hrows + (size_t)s2 * 64;
        const uint* r3 = hrows + (size_t)s3 * 64;
        uint v0 = r0[lane];
        uint v1 = r1[lane];
        uint v2 = r2[lane];
        uint v3 = r3[lane];
        float w0 = ew[j];
        float w1 = ew[c1];
        float w2 = ew[c2];
        float w3 = ew[c3];
        w1 = (i1 < end) ? w1 : 0.f;
        w2 = (i2 < end) ? w2 : 0.f;
        w3 = (i3 < end) ? w3 : 0.f;
        denom += (w0 + w1) + (w2 + w3);
        float2 f0 = h2_to_f2(v0), f1 = h2_to_f2(v1);
        float2 f2 = h2_to_f2(v2), f3 = h2_to_f2(v3);
        acc0 += w0 * f0.x + w1 * f1.x + w2 * f2.x + w3 * f3.x;
        acc1 += w0 * f0.y + w1 * f1.y + w2 * f2.y + w3 * f3.y;
    }

    float inv = 1.0f / denom;
    float2 b2 = ((const float2*)bias)[lane];
    float o0 = acc0 * inv + b2.x;
    float o1 = acc1 * inv + b2.y;
    if (FINAL) {
        ((float2*)out_f)[(size_t)wid * 64 + lane] = make_float2(o0, o1);
    } else {
        o0 = (o0 > 0.f) ? o0 : (__expf(o0) - 1.0f);   // ELU
        o1 = (o1 > 0.f) ? o1 : (__expf(o1) - 1.0f);
        __bf16 h0 = (__bf16)o0, h1 = (__bf16)o1;
        bf16x2 ph = { h0, h1 };
        bf16x2 pl = { (__bf16)(o0 - (float)h0), (__bf16)(o1 - (float)h1) };
        ((bf16x2*)a_hi)[(size_t)wid * 64 + lane] = ph;
        ((bf16x2*)a_lo)[(size_t)wid * 64 + lane] = pl;
    }
}

// ============================ launch =====================================

extern "C" void kernel_launch(void* const* d_in, const int* in_sizes, int n_in,
                              void* d_out, int out_size, void* d_ws, size_t ws_size,
                              hipStream_t stream) {
    const float* x = (const float*)d_in[0];
    const int* ei = (const int*)d_in[1];
    int N = in_sizes[0] / 128;
    int E = in_sizes[1] / 2;
    const int* src = ei;
    const int* dst = ei + E;

    const float* Wl_[3] = { (const float*)d_in[2], (const float*)d_in[6], (const float*)d_in[10] };
    const float* asl[3] = { (const float*)d_in[3], (const float*)d_in[7], (const float*)d_in[11] };
    const float* adl[3] = { (const float*)d_in[4], (const float*)d_in[8], (const float*)d_in[12] };
    const float* bl[3]  = { (const float*)d_in[5], (const float*)d_in[9], (const float*)d_in[13] };

    // ---- workspace (~41 MB) ----
    size_t nfeat = (size_t)N * 128;
    char* p = (char*)d_ws;
    _Float16* Hh = (_Float16*)p; p += nfeat * 2;       // fp16 gather table
    __bf16* Wfh = (__bf16*)p; p += 3 * 16384 * 2;      // fragment-ordered W hi
    __bf16* Wfl = (__bf16*)p; p += 3 * 16384 * 2;      // fragment-ordered W lo
    float* asrc = (float*)p;  p += (size_t)N * 4;
    float* adst = (float*)p;  p += (size_t)N * 4;
    int* off    = (int*)p;    p += (size_t)(N + 1) * 4;
    int* bsum   = (int*)p;    p += 4096 * 4;
    float* ew    = (float*)p; p += (size_t)E * 4;      // per-edge softmax weights
    float* wself = (float*)p; p += (size_t)N * 4;      // self-loop weights
    int* csr    = (int*)p;

    // Scratch that ALIASES the Hh region (dead until the first gemm, which
    // runs after CSR build): padded deg counters (N*128B = 12.8MB) then the
    // per-edge rank array (6.4MB). 19.2MB <= Hh's 25.6MB.
    int* cpad = (int*)Hh;
    int* rank = (int*)((char*)Hh + ((size_t)N << CPAD) * sizeof(int) / 1);

    // activations ping-pong through d_out: hi then lo bf16 (= 51.2 MB total)
    __bf16* A_hi = (__bf16*)d_out;
    __bf16* A_lo = A_hi + nfeat;

    int G = (N + 1023) / 1024;

    // ---- CSR build (grouped by dst) ----
    hipMemsetAsync(cpad, 0, ((size_t)N << CPAD) * sizeof(int), stream);
    count_deg_rank<<<2048, 256, 0, stream>>>(dst, cpad, rank, E);
    scan_block_k<<<G, 256, 0, stream>>>(cpad, off, bsum, N);
    scan_bsum_k<<<1, 1024, 0, stream>>>(bsum, G);
    add_bsum_k<<<(N + 256) / 256, 256, 0, stream>>>(off, bsum, N, E);
    fill_scatter<<<2048, 256, 0, stream>>>(src, dst, rank, off, csr, E);

    // ---- splits ----
    split_w_k<<<dim3(64, 3), 256, 0, stream>>>(Wl_[0], Wl_[1], Wl_[2], Wfh, Wfl);
    int n4 = (int)(nfeat / 4);
    split_x_k<<<(n4 + 255) / 256, 256, 0, stream>>>(x, A_hi, A_lo, n4);

    int gemm_blocks = (N + 63) / 64;
    int wave_blocks = (N + 3) / 4;
    int ew_blocks = (N + 15) / 16;

    for (int l = 0; l < 3; ++l) {
        gemm_split<<<gemm_blocks, 256, 0, stream>>>(
            A_hi, A_lo, Wfh + (size_t)l * 16384, Wfl + (size_t)l * 16384,
            asl[l], adl[l], Hh, asrc, adst, N);
        edge_w_k<<<ew_blocks, 256, 0, stream>>>(asrc, adst, off, csr, ew, wself, N);
        if (l < 2) {
            aggregate_k<0><<<wave_blocks, 256, 0, stream>>>(
                Hh, ew, wself, off, csr, bl[l], nullptr, A_hi, A_lo, N, E);
        } else {
            aggregate_k<1><<<wave_blocks, 256, 0, stream>>>(
                Hh, ew, wself, off, csr, bl[l], (float*)d_out, nullptr, nullptr, N, E);
        }
    }
}